// Round 1
// baseline (525.026 us; speedup 1.0000x reference)
//
// R1: sparse MoE via gather + 2 fused bf16-MFMA grouped GEMMs (m97 structure).
// ws layout: Wgu_bf16 64MB | Wd_bf16 32MB | Xg 18MB | H 36MB | slot_token | slot_w | meta
#include <hip/hip_runtime.h>
#include <stdint.h>

#define TOKS 4096
#define DIM  1024
#define HID  2048
#define OUTD 1024
#define NE   8
#define MP   9216   // max padded rows (8192 + 8*127 -> <= 9216)
#define NBR  72     // MP/128

typedef __bf16 bf16;
typedef bf16 bf16x8 __attribute__((ext_vector_type(8)));
typedef float f32x4 __attribute__((ext_vector_type(4)));
typedef __attribute__((address_space(1))) void gvoid;
typedef __attribute__((address_space(3))) void lvoid;

// ---- workspace byte offsets ----
#define WGU_OFF  0ull                         // 8*4096*1024*2  = 67108864
#define WD_OFF   (WGU_OFF + 67108864ull)      // 8*1024*2048*2  = 33554432
#define XG_OFF   (WD_OFF  + 33554432ull)      // MP*1024*2      = 18874368
#define H_OFF    (XG_OFF  + 18874368ull)      // MP*2048*2      = 37748736
#define TK_OFF   (H_OFF   + 37748736ull)      // MP*4
#define SW_OFF   (TK_OFF  + 36864ull)         // MP*4
#define META_OFF (SW_OFF  + 36864ull)
// meta ints: [0..8) counts, [8..16) offs, [16..24) cursors, [24..96) table

__device__ __forceinline__ unsigned short f2bf(float f) {
  union { float f; unsigned u; } v; v.f = f;
  unsigned r = (v.u + 0x7FFFu + ((v.u >> 16) & 1u)) >> 16;
  return (unsigned short)r;
}
__device__ __forceinline__ unsigned pack2(float a, float b) {
  return (unsigned)f2bf(a) | ((unsigned)f2bf(b) << 16);
}
__device__ __forceinline__ void cp16(const void* g, void* l) {
  __builtin_amdgcn_global_load_lds((gvoid*)(void*)g, (lvoid*)l, 16, 0, 0);
}

// ---------- small kernels ----------
__global__ void zero_out_kernel(float4* __restrict__ out) {
  out[blockIdx.x * 256 + threadIdx.x] = float4{0.f, 0.f, 0.f, 0.f};
}

__global__ void init_kernel(int* __restrict__ slot_token, int* __restrict__ counts) {
  int gid = blockIdx.x * 256 + threadIdx.x;
  if (gid < MP) slot_token[gid] = -1;
  if (gid < NE) counts[gid] = 0;
}

__global__ void count_kernel(const int* __restrict__ idx, int* __restrict__ counts) {
  int gid = blockIdx.x * 256 + threadIdx.x;
  if (gid < TOKS * 2) atomicAdd(&counts[idx[gid]], 1);
}

__global__ void offsets_kernel(int* __restrict__ meta) {
  if (threadIdx.x != 0) return;
  int* counts = meta; int* offs = meta + 8; int* cursors = meta + 16; int* table = meta + 24;
  int cum = 0;
  for (int e = 0; e < NE; ++e) {
    offs[e] = cum; cursors[e] = 0;
    int nb = (counts[e] + 127) >> 7;
    int bb = cum >> 7;
    for (int b = 0; b < nb; ++b) table[bb + b] = e;
    cum += nb << 7;
  }
  for (int b = cum >> 7; b < NBR; ++b) table[b] = -1;
}

__global__ void scatter_kernel(const int* __restrict__ idx, const float* __restrict__ wts,
                               int* __restrict__ meta, int* __restrict__ slot_token,
                               float* __restrict__ slot_w) {
  int gid = blockIdx.x * 256 + threadIdx.x;
  if (gid >= TOKS * 2) return;
  int e = idx[gid];
  int pos = meta[8 + e] + atomicAdd(&meta[16 + e], 1);
  slot_token[pos] = gid >> 1;
  slot_w[pos] = wts[gid];
}

__global__ void gather_kernel(const float* __restrict__ X, const int* __restrict__ slot_token,
                              uint4* __restrict__ Xg) {
  int gid = blockIdx.x * 256 + threadIdx.x;   // MP*128 threads, 8 elems each
  int row = gid >> 7, j = (gid & 127) << 3;
  int t = slot_token[row];
  uint4 o;
  if (t >= 0) {
    const float4* p = (const float4*)(X + (size_t)t * DIM + j);
    float4 a = p[0], b = p[1];
    o.x = pack2(a.x, a.y); o.y = pack2(a.z, a.w);
    o.z = pack2(b.x, b.y); o.w = pack2(b.z, b.w);
  } else {
    o = uint4{0u, 0u, 0u, 0u};
  }
  Xg[gid] = o;
}

__global__ void convert_kernel(const float4* __restrict__ src, uint2* __restrict__ dst, int n4) {
  int i = blockIdx.x * 256 + threadIdx.x;
  if (i >= n4) return;
  float4 v = src[i];
  uint2 o; o.x = pack2(v.x, v.y); o.y = pack2(v.z, v.w);
  dst[i] = o;
}

// ---------- GEMM1: h = silu(Xg*Wg^T) * (Xg*Wu^T), bf16 in/out ----------
// grid (32, 72): x = H col-block (64 cols of gate + matching up), y = row-block
__global__ __launch_bounds__(256) void gemm1_kernel(
    const unsigned short* __restrict__ Xg,   // [MP, DIM]
    const unsigned short* __restrict__ Wgu,  // [NE, 2*HID, DIM]
    unsigned short* __restrict__ Hbuf,       // [MP, HID]
    const int* __restrict__ table) {
  int e = table[blockIdx.y];
  if (e < 0) return;
  const int tid = threadIdx.x;
  const int lane = tid & 63, wave = tid >> 6;
  const int wm = wave >> 1, wn = wave & 1;
  const int lr = lane & 15, quad = lane >> 4;

  __shared__ bf16 As[128 * 32];
  __shared__ bf16 Bg[64 * 32];
  __shared__ bf16 Bu[64 * 32];

  const unsigned short* A_base  = Xg  + (size_t)blockIdx.y * 128 * DIM;
  const unsigned short* Wg_base = Wgu + (size_t)e * 2 * HID * DIM + (size_t)(blockIdx.x * 64) * DIM;
  const unsigned short* Wu_base = Wg_base + (size_t)HID * DIM;

  const int srow = tid >> 2, skc = (tid & 3) * 8;

  f32x4 accg[4][2] = {}; f32x4 accu[4][2] = {};

  for (int kt = 0; kt < DIM / 32; ++kt) {
    const int kb = kt * 32;
    cp16(A_base  + (size_t)srow * DIM + kb + skc,        (void*)(As + srow * 32 + skc));
    cp16(A_base  + (size_t)(srow + 64) * DIM + kb + skc, (void*)(As + (srow + 64) * 32 + skc));
    cp16(Wg_base + (size_t)srow * DIM + kb + skc,        (void*)(Bg + srow * 32 + skc));
    cp16(Wu_base + (size_t)srow * DIM + kb + skc,        (void*)(Bu + srow * 32 + skc));
    __syncthreads();
    bf16x8 a[4], bg[2], bu[2];
#pragma unroll
    for (int i = 0; i < 4; ++i)
      a[i] = *(const bf16x8*)(As + (wm * 64 + i * 16 + lr) * 32 + quad * 8);
#pragma unroll
    for (int j = 0; j < 2; ++j) {
      bg[j] = *(const bf16x8*)(Bg + (wn * 32 + j * 16 + lr) * 32 + quad * 8);
      bu[j] = *(const bf16x8*)(Bu + (wn * 32 + j * 16 + lr) * 32 + quad * 8);
    }
#pragma unroll
    for (int i = 0; i < 4; ++i)
#pragma unroll
      for (int j = 0; j < 2; ++j) {
        accg[i][j] = __builtin_amdgcn_mfma_f32_16x16x32_bf16(a[i], bg[j], accg[i][j], 0, 0, 0);
        accu[i][j] = __builtin_amdgcn_mfma_f32_16x16x32_bf16(a[i], bu[j], accu[i][j], 0, 0, 0);
      }
    __syncthreads();
  }

  const int rowBase = blockIdx.y * 128 + wm * 64;
  const int colBase = blockIdx.x * 64 + wn * 32;
#pragma unroll
  for (int i = 0; i < 4; ++i)
#pragma unroll
    for (int r = 0; r < 4; ++r) {
      int row = rowBase + i * 16 + quad * 4 + r;
#pragma unroll
      for (int j = 0; j < 2; ++j) {
        float g = accg[i][j][r], u = accu[i][j][r];
        float s = g / (1.0f + __expf(-g));
        Hbuf[(size_t)row * HID + colBase + j * 16 + lr] = f2bf(s * u);
      }
    }
}

// ---------- GEMM2: out[t] += w * (H * Wd^T), atomic scatter ----------
// grid (8, 72): x = OUT col-block (128), y = row-block
__global__ __launch_bounds__(256) void gemm2_kernel(
    const unsigned short* __restrict__ Hbuf, // [MP, HID]
    const unsigned short* __restrict__ Wd,   // [NE, OUTD, HID]
    float* __restrict__ out,                 // [TOKS, OUTD]
    const int* __restrict__ table,
    const int* __restrict__ slot_token,
    const float* __restrict__ slot_w) {
  int e = table[blockIdx.y];
  if (e < 0) return;
  const int tid = threadIdx.x;
  const int lane = tid & 63, wave = tid >> 6;
  const int wm = wave >> 1, wn = wave & 1;
  const int lr = lane & 15, quad = lane >> 4;

  __shared__ bf16 As[128 * 32];
  __shared__ bf16 Bs[128 * 32];

  const unsigned short* A_base = Hbuf + (size_t)blockIdx.y * 128 * HID;
  const unsigned short* B_base = Wd + (size_t)e * OUTD * HID + (size_t)(blockIdx.x * 128) * HID;

  const int srow = tid >> 2, skc = (tid & 3) * 8;

  f32x4 acc[4][4] = {};

  for (int kt = 0; kt < HID / 32; ++kt) {
    const int kb = kt * 32;
    cp16(A_base + (size_t)srow * HID + kb + skc,        (void*)(As + srow * 32 + skc));
    cp16(A_base + (size_t)(srow + 64) * HID + kb + skc, (void*)(As + (srow + 64) * 32 + skc));
    cp16(B_base + (size_t)srow * HID + kb + skc,        (void*)(Bs + srow * 32 + skc));
    cp16(B_base + (size_t)(srow + 64) * HID + kb + skc, (void*)(Bs + (srow + 64) * 32 + skc));
    __syncthreads();
    bf16x8 a[4], b[4];
#pragma unroll
    for (int i = 0; i < 4; ++i)
      a[i] = *(const bf16x8*)(As + (wm * 64 + i * 16 + lr) * 32 + quad * 8);
#pragma unroll
    for (int j = 0; j < 4; ++j)
      b[j] = *(const bf16x8*)(Bs + (wn * 64 + j * 16 + lr) * 32 + quad * 8);
#pragma unroll
    for (int i = 0; i < 4; ++i)
#pragma unroll
      for (int j = 0; j < 4; ++j)
        acc[i][j] = __builtin_amdgcn_mfma_f32_16x16x32_bf16(a[i], b[j], acc[i][j], 0, 0, 0);
    __syncthreads();
  }

  const int rowBase = blockIdx.y * 128 + wm * 64;
  const int colBase = blockIdx.x * 128 + wn * 64;
#pragma unroll
  for (int i = 0; i < 4; ++i)
#pragma unroll
    for (int r = 0; r < 4; ++r) {
      int row = rowBase + i * 16 + quad * 4 + r;
      int t = slot_token[row];
      if (t >= 0) {
        float w = slot_w[row];
#pragma unroll
        for (int j = 0; j < 4; ++j)
          atomicAdd(&out[(size_t)t * OUTD + colBase + j * 16 + lr], w * acc[i][j][r]);
      }
    }
}

extern "C" void kernel_launch(void* const* d_in, const int* in_sizes, int n_in,
                              void* d_out, int out_size, void* d_ws, size_t ws_size,
                              hipStream_t stream) {
  const float* X     = (const float*)d_in[0];
  const int*   idx   = (const int*)d_in[1];
  const float* wts   = (const float*)d_in[2];
  const float* WguF  = (const float*)d_in[3];
  const float* WdF   = (const float*)d_in[4];
  float* out = (float*)d_out;

  char* base = (char*)d_ws;
  unsigned short* Wgu = (unsigned short*)(base + WGU_OFF);
  unsigned short* Wd  = (unsigned short*)(base + WD_OFF);
  unsigned short* Xg  = (unsigned short*)(base + XG_OFF);
  unsigned short* Hb  = (unsigned short*)(base + H_OFF);
  int*   slot_token = (int*)(base + TK_OFF);
  float* slot_w     = (float*)(base + SW_OFF);
  int*   meta       = (int*)(base + META_OFF);
  int*   table      = meta + 24;

  zero_out_kernel<<<(TOKS * OUTD / 4) / 256, 256, 0, stream>>>((float4*)out);
  init_kernel<<<MP / 256, 256, 0, stream>>>(slot_token, meta);
  count_kernel<<<(TOKS * 2) / 256, 256, 0, stream>>>(idx, meta);
  offsets_kernel<<<1, 64, 0, stream>>>(meta);
  scatter_kernel<<<(TOKS * 2) / 256, 256, 0, stream>>>(idx, wts, meta, slot_token, slot_w);
  gather_kernel<<<(MP * 128) / 256, 256, 0, stream>>>(X, slot_token, (uint4*)Xg);
  convert_kernel<<<(NE * 2 * HID * DIM / 4) / 256, 256, 0, stream>>>(
      (const float4*)WguF, (uint2*)Wgu, NE * 2 * HID * DIM / 4);
  convert_kernel<<<(NE * OUTD * HID / 4) / 256, 256, 0, stream>>>(
      (const float4*)WdF, (uint2*)Wd, NE * OUTD * HID / 4);
  gemm1_kernel<<<dim3(HID / 64, NBR), 256, 0, stream>>>(Xg, Wgu, Hb, table);
  gemm2_kernel<<<dim3(OUTD / 128, NBR), 256, 0, stream>>>(Hb, Wd, out, table, slot_token, slot_w);
}

// Round 2
// 493.359 us; speedup vs baseline: 1.0642x; 1.0642x over previous
//
// R2: wave-aggregated routing, Obuf+combine instead of gemm2 atomics,
//     XOR-swizzled LDS staging (conflict-free ds_read_b128).
// ws: Wgu_bf16 64MB (Obuf fp32 aliases it after gemm1) | Wd_bf16 | Xg | H | slots | meta | tok2slot
#include <hip/hip_runtime.h>
#include <stdint.h>

#define TOKS 4096
#define DIM  1024
#define HID  2048
#define OUTD 1024
#define NE   8
#define MP   9216   // max padded rows (8192 + 8*127 -> <= 9216)
#define NBR  72     // MP/128

typedef __bf16 bf16;
typedef bf16 bf16x8 __attribute__((ext_vector_type(8)));
typedef float f32x4 __attribute__((ext_vector_type(4)));
typedef __attribute__((address_space(1))) void gvoid;
typedef __attribute__((address_space(3))) void lvoid;

// ---- workspace byte offsets ----
#define WGU_OFF  0ull                         // 8*4096*1024*2  = 67108864 ; Obuf fp32 (MP*1024*4=37.7MB) aliases this
#define WD_OFF   (WGU_OFF + 67108864ull)      // 8*1024*2048*2  = 33554432
#define XG_OFF   (WD_OFF  + 33554432ull)      // MP*1024*2      = 18874368
#define H_OFF    (XG_OFF  + 18874368ull)      // MP*2048*2      = 37748736
#define TK_OFF   (H_OFF   + 37748736ull)      // MP*4
#define SW_OFF   (TK_OFF  + 36864ull)         // MP*4
#define META_OFF (SW_OFF  + 36864ull)         // 96 ints: [0..8) counts, [8..16) offs, [16..24) cursors, [24..96) table
#define T2S_OFF  (META_OFF + 1024ull)         // TOKS*2 ints

__device__ __forceinline__ unsigned short f2bf(float f) {
  union { float f; unsigned u; } v; v.f = f;
  unsigned r = (v.u + 0x7FFFu + ((v.u >> 16) & 1u)) >> 16;
  return (unsigned short)r;
}
__device__ __forceinline__ unsigned pack2(float a, float b) {
  return (unsigned)f2bf(a) | ((unsigned)f2bf(b) << 16);
}
__device__ __forceinline__ void cp16(const void* g, void* l) {
  __builtin_amdgcn_global_load_lds((gvoid*)(void*)g, (lvoid*)l, 16, 0, 0);
}

// ---------- small kernels ----------
__global__ void init_kernel(int* __restrict__ slot_token, int* __restrict__ counts) {
  int gid = blockIdx.x * 256 + threadIdx.x;
  if (gid < MP) slot_token[gid] = -1;
  if (gid < NE) counts[gid] = 0;
}

__global__ void count_kernel(const int* __restrict__ idx, int* __restrict__ counts) {
  int gid = blockIdx.x * 256 + threadIdx.x;
  int lane = threadIdx.x & 63;
  int e = (gid < TOKS * 2) ? idx[gid] : -1;
#pragma unroll
  for (int ex = 0; ex < NE; ++ex) {
    unsigned long long mask = __ballot(e == ex);
    if (lane == 0 && mask) atomicAdd(&counts[ex], __popcll(mask));
  }
}

__global__ void offsets_kernel(int* __restrict__ meta) {
  if (threadIdx.x != 0) return;
  int* counts = meta; int* offs = meta + 8; int* cursors = meta + 16; int* table = meta + 24;
  int cum = 0;
  for (int e = 0; e < NE; ++e) {
    offs[e] = cum; cursors[e] = 0;
    int nb = (counts[e] + 127) >> 7;
    int bb = cum >> 7;
    for (int b = 0; b < nb; ++b) table[bb + b] = e;
    cum += nb << 7;
  }
  for (int b = cum >> 7; b < NBR; ++b) table[b] = -1;
}

__global__ void scatter_kernel(const int* __restrict__ idx, const float* __restrict__ wts,
                               int* __restrict__ meta, int* __restrict__ slot_token,
                               float* __restrict__ slot_w, int* __restrict__ tok2slot) {
  int gid = blockIdx.x * 256 + threadIdx.x;
  int lane = threadIdx.x & 63;
  int e = (gid < TOKS * 2) ? idx[gid] : -1;
  int pos = -1;
#pragma unroll
  for (int ex = 0; ex < NE; ++ex) {
    unsigned long long mask = __ballot(e == ex);
    if (e == ex) {
      int rank = __popcll(mask & ((1ull << lane) - 1ull));
      int leader = __ffsll(mask) - 1;
      int base = 0;
      if (lane == leader) base = atomicAdd(&meta[16 + ex], __popcll(mask));
      base = __shfl(base, leader);
      pos = meta[8 + ex] + base + rank;
    }
  }
  if (e >= 0) {
    slot_token[pos] = gid >> 1;
    slot_w[pos] = wts[gid];
    tok2slot[gid] = pos;
  }
}

__global__ void gather_kernel(const float* __restrict__ X, const int* __restrict__ slot_token,
                              uint4* __restrict__ Xg) {
  int gid = blockIdx.x * 256 + threadIdx.x;   // MP*128 threads, 8 elems each
  int row = gid >> 7, j = (gid & 127) << 3;
  int t = slot_token[row];
  uint4 o;
  if (t >= 0) {
    const float4* p = (const float4*)(X + (size_t)t * DIM + j);
    float4 a = p[0], b = p[1];
    o.x = pack2(a.x, a.y); o.y = pack2(a.z, a.w);
    o.z = pack2(b.x, b.y); o.w = pack2(b.z, b.w);
  } else {
    o = uint4{0u, 0u, 0u, 0u};
  }
  Xg[gid] = o;
}

__global__ void convert_kernel(const float4* __restrict__ src, uint2* __restrict__ dst, int n4) {
  int i = blockIdx.x * 256 + threadIdx.x;
  if (i >= n4) return;
  float4 v = src[i];
  uint2 o; o.x = pack2(v.x, v.y); o.y = pack2(v.z, v.w);
  dst[i] = o;
}

__global__ void combine_kernel(const float* __restrict__ Obuf, const int* __restrict__ tok2slot,
                               const float* __restrict__ slot_w, float4* __restrict__ out) {
  int t = blockIdx.x, c = threadIdx.x;            // 4096 blocks x 256 threads (float4/thread)
  int s0 = tok2slot[2 * t], s1 = tok2slot[2 * t + 1];
  float w0 = slot_w[s0], w1 = slot_w[s1];
  float4 a = ((const float4*)(Obuf + (size_t)s0 * OUTD))[c];
  float4 b = ((const float4*)(Obuf + (size_t)s1 * OUTD))[c];
  out[(size_t)t * (OUTD / 4) + c] =
      float4{w0 * a.x + w1 * b.x, w0 * a.y + w1 * b.y, w0 * a.z + w1 * b.z, w0 * a.w + w1 * b.w};
}

// ---------- GEMM1: h = silu(Xg*Wg^T) * (Xg*Wu^T), bf16 in/out ----------
// grid (32, 72): x = H col-block (64 cols of gate + matching up), y = row-block
__global__ __launch_bounds__(256) void gemm1_kernel(
    const unsigned short* __restrict__ Xg,   // [MP, DIM]
    const unsigned short* __restrict__ Wgu,  // [NE, 2*HID, DIM]
    unsigned short* __restrict__ Hbuf,       // [MP, HID]
    const int* __restrict__ table) {
  int e = table[blockIdx.y];
  if (e < 0) return;
  const int tid = threadIdx.x;
  const int lane = tid & 63, wave = tid >> 6;
  const int wm = wave >> 1, wn = wave & 1;
  const int lr = lane & 15, quad = lane >> 4;

  __shared__ bf16 As[128 * 32];
  __shared__ bf16 Bg[64 * 32];
  __shared__ bf16 Bu[64 * 32];

  const unsigned short* A_base  = Xg  + (size_t)blockIdx.y * 128 * DIM;
  const unsigned short* Wg_base = Wgu + (size_t)e * 2 * HID * DIM + (size_t)(blockIdx.x * 64) * DIM;
  const unsigned short* Wu_base = Wg_base + (size_t)HID * DIM;

  // XOR-swizzled staging: LDS chunk (row, c) holds global chunk (row, c ^ ((row>>1)&3)).
  const int srow = tid >> 2;
  const int sldc = (tid & 3) * 8;                          // LDS column (lane-contiguous)
  const int sgc  = ((tid & 3) ^ ((srow >> 1) & 3)) * 8;    // swizzled global column
  // Fragment read: global chunk 'quad' of row r lives at LDS chunk quad ^ ((r>>1)&3).
  const int cq = (quad ^ ((lr >> 1) & 3)) * 8;

  f32x4 accg[4][2] = {}; f32x4 accu[4][2] = {};

  for (int kt = 0; kt < DIM / 32; ++kt) {
    const int kb = kt * 32;
    cp16(A_base  + (size_t)srow * DIM + kb + sgc,        (void*)(As + srow * 32 + sldc));
    cp16(A_base  + (size_t)(srow + 64) * DIM + kb + sgc, (void*)(As + (srow + 64) * 32 + sldc));
    cp16(Wg_base + (size_t)srow * DIM + kb + sgc,        (void*)(Bg + srow * 32 + sldc));
    cp16(Wu_base + (size_t)srow * DIM + kb + sgc,        (void*)(Bu + srow * 32 + sldc));
    __syncthreads();
    bf16x8 a[4], bg[2], bu[2];
#pragma unroll
    for (int i = 0; i < 4; ++i)
      a[i] = *(const bf16x8*)(As + (wm * 64 + i * 16 + lr) * 32 + cq);
#pragma unroll
    for (int j = 0; j < 2; ++j) {
      bg[j] = *(const bf16x8*)(Bg + (wn * 32 + j * 16 + lr) * 32 + cq);
      bu[j] = *(const bf16x8*)(Bu + (wn * 32 + j * 16 + lr) * 32 + cq);
    }
#pragma unroll
    for (int i = 0; i < 4; ++i)
#pragma unroll
      for (int j = 0; j < 2; ++j) {
        accg[i][j] = __builtin_amdgcn_mfma_f32_16x16x32_bf16(a[i], bg[j], accg[i][j], 0, 0, 0);
        accu[i][j] = __builtin_amdgcn_mfma_f32_16x16x32_bf16(a[i], bu[j], accu[i][j], 0, 0, 0);
      }
    __syncthreads();
  }

  const int rowBase = blockIdx.y * 128 + wm * 64;
  const int colBase = blockIdx.x * 64 + wn * 32;
#pragma unroll
  for (int i = 0; i < 4; ++i)
#pragma unroll
    for (int r = 0; r < 4; ++r) {
      int row = rowBase + i * 16 + quad * 4 + r;
#pragma unroll
      for (int j = 0; j < 2; ++j) {
        float g = accg[i][j][r], u = accu[i][j][r];
        float s = g / (1.0f + __expf(-g));
        Hbuf[(size_t)row * HID + colBase + j * 16 + lr] = f2bf(s * u);
      }
    }
}

// ---------- GEMM2: Obuf[slot] = H * Wd^T (no atomics; combine gathers) ----------
// grid (8, 72): x = OUT col-block (128), y = row-block
__global__ __launch_bounds__(256) void gemm2_kernel(
    const unsigned short* __restrict__ Hbuf, // [MP, HID]
    const unsigned short* __restrict__ Wd,   // [NE, OUTD, HID]
    float* __restrict__ Obuf,                // [MP, OUTD]
    const int* __restrict__ table) {
  int e = table[blockIdx.y];
  if (e < 0) return;
  const int tid = threadIdx.x;
  const int lane = tid & 63, wave = tid >> 6;
  const int wm = wave >> 1, wn = wave & 1;
  const int lr = lane & 15, quad = lane >> 4;

  __shared__ bf16 As[128 * 32];
  __shared__ bf16 Bs[128 * 32];

  const unsigned short* A_base = Hbuf + (size_t)blockIdx.y * 128 * HID;
  const unsigned short* B_base = Wd + (size_t)e * OUTD * HID + (size_t)(blockIdx.x * 128) * HID;

  const int srow = tid >> 2;
  const int sldc = (tid & 3) * 8;
  const int sgc  = ((tid & 3) ^ ((srow >> 1) & 3)) * 8;
  const int cq = (quad ^ ((lr >> 1) & 3)) * 8;

  f32x4 acc[4][4] = {};

  for (int kt = 0; kt < HID / 32; ++kt) {
    const int kb = kt * 32;
    cp16(A_base + (size_t)srow * HID + kb + sgc,        (void*)(As + srow * 32 + sldc));
    cp16(A_base + (size_t)(srow + 64) * HID + kb + sgc, (void*)(As + (srow + 64) * 32 + sldc));
    cp16(B_base + (size_t)srow * HID + kb + sgc,        (void*)(Bs + srow * 32 + sldc));
    cp16(B_base + (size_t)(srow + 64) * HID + kb + sgc, (void*)(Bs + (srow + 64) * 32 + sldc));
    __syncthreads();
    bf16x8 a[4], b[4];
#pragma unroll
    for (int i = 0; i < 4; ++i)
      a[i] = *(const bf16x8*)(As + (wm * 64 + i * 16 + lr) * 32 + cq);
#pragma unroll
    for (int j = 0; j < 4; ++j)
      b[j] = *(const bf16x8*)(Bs + (wn * 64 + j * 16 + lr) * 32 + cq);
#pragma unroll
    for (int i = 0; i < 4; ++i)
#pragma unroll
      for (int j = 0; j < 4; ++j)
        acc[i][j] = __builtin_amdgcn_mfma_f32_16x16x32_bf16(a[i], b[j], acc[i][j], 0, 0, 0);
    __syncthreads();
  }

  const int rowBase = blockIdx.y * 128 + wm * 64;
  const int colBase = blockIdx.x * 128 + wn * 64;
#pragma unroll
  for (int i = 0; i < 4; ++i)
#pragma unroll
    for (int r = 0; r < 4; ++r) {
      int row = rowBase + i * 16 + quad * 4 + r;
      float* Orow = Obuf + (size_t)row * OUTD + colBase;
#pragma unroll
      for (int j = 0; j < 4; ++j)
        Orow[j * 16 + lr] = acc[i][j][r];
    }
}

extern "C" void kernel_launch(void* const* d_in, const int* in_sizes, int n_in,
                              void* d_out, int out_size, void* d_ws, size_t ws_size,
                              hipStream_t stream) {
  const float* X     = (const float*)d_in[0];
  const int*   idx   = (const int*)d_in[1];
  const float* wts   = (const float*)d_in[2];
  const float* WguF  = (const float*)d_in[3];
  const float* WdF   = (const float*)d_in[4];
  float* out = (float*)d_out;

  char* base = (char*)d_ws;
  unsigned short* Wgu = (unsigned short*)(base + WGU_OFF);
  unsigned short* Wd  = (unsigned short*)(base + WD_OFF);
  unsigned short* Xg  = (unsigned short*)(base + XG_OFF);
  unsigned short* Hb  = (unsigned short*)(base + H_OFF);
  float* Obuf         = (float*)(base + WGU_OFF);   // aliases Wgu (dead after gemm1)
  int*   slot_token = (int*)(base + TK_OFF);
  float* slot_w     = (float*)(base + SW_OFF);
  int*   meta       = (int*)(base + META_OFF);
  int*   table      = meta + 24;
  int*   tok2slot   = (int*)(base + T2S_OFF);

  init_kernel<<<MP / 256, 256, 0, stream>>>(slot_token, meta);
  count_kernel<<<(TOKS * 2) / 256, 256, 0, stream>>>(idx, meta);
  offsets_kernel<<<1, 64, 0, stream>>>(meta);
  scatter_kernel<<<(TOKS * 2) / 256, 256, 0, stream>>>(idx, wts, meta, slot_token, slot_w, tok2slot);
  gather_kernel<<<(MP * 128) / 256, 256, 0, stream>>>(X, slot_token, (uint4*)Xg);
  convert_kernel<<<(NE * 2 * HID * DIM / 4) / 256, 256, 0, stream>>>(
      (const float4*)WguF, (uint2*)Wgu, NE * 2 * HID * DIM / 4);
  convert_kernel<<<(NE * OUTD * HID / 4) / 256, 256, 0, stream>>>(
      (const float4*)WdF, (uint2*)Wd, NE * OUTD * HID / 4);
  gemm1_kernel<<<dim3(HID / 64, NBR), 256, 0, stream>>>(Xg, Wgu, Hb, table);
  gemm2_kernel<<<dim3(OUTD / 128, NBR), 256, 0, stream>>>(Hb, Wd, Obuf, table);
  combine_kernel<<<TOKS, 256, 0, stream>>>(Obuf, tok2slot, slot_w, (float4*)out);
}

// Round 3
// 438.643 us; speedup vs baseline: 1.1969x; 1.1247x over previous
//
// R3: BK=64 GEMMs (halved barriers, 32KB LDS, xor-row swizzle), single fused
// routing kernel, merged weight-convert, 6 launches total.
// ws: Wgu_bf16 64MB (Obuf fp32 aliases after gemm1) | Wd_bf16 | Xg | H | slots | meta | tok2slot
#include <hip/hip_runtime.h>
#include <stdint.h>

#define TOKS 4096
#define DIM  1024
#define HID  2048
#define OUTD 1024
#define NE   8
#define MP   9216   // max padded rows (8192 + 8*127 -> <= 9216)
#define NBR  72     // MP/128

typedef __bf16 bf16;
typedef bf16 bf16x8 __attribute__((ext_vector_type(8)));
typedef float f32x4 __attribute__((ext_vector_type(4)));
typedef __attribute__((address_space(1))) void gvoid;
typedef __attribute__((address_space(3))) void lvoid;

// ---- workspace byte offsets ----
#define WGU_OFF  0ull                         // 8*4096*1024*2  = 67108864 ; Obuf fp32 aliases
#define WD_OFF   (WGU_OFF + 67108864ull)      // 8*1024*2048*2  = 33554432
#define XG_OFF   (WD_OFF  + 33554432ull)      // MP*1024*2      = 18874368
#define H_OFF    (XG_OFF  + 18874368ull)      // MP*2048*2      = 37748736
#define TK_OFF   (H_OFF   + 37748736ull)      // MP*4
#define META_OFF (TK_OFF  + 36864ull)         // table: NBR ints
#define T2S_OFF  (META_OFF + 1024ull)         // TOKS*2 ints

__device__ __forceinline__ unsigned short f2bf(float f) {
  union { float f; unsigned u; } v; v.f = f;
  unsigned r = (v.u + 0x7FFFu + ((v.u >> 16) & 1u)) >> 16;
  return (unsigned short)r;
}
__device__ __forceinline__ unsigned pack2(float a, float b) {
  return (unsigned)f2bf(a) | ((unsigned)f2bf(b) << 16);
}
__device__ __forceinline__ void cp16(const void* g, void* l) {
  __builtin_amdgcn_global_load_lds((gvoid*)(void*)g, (lvoid*)l, 16, 0, 0);
}

// ---------- routing: init + histogram + offsets + scatter, one block ----------
__global__ __launch_bounds__(1024) void route_kernel(const int* __restrict__ idx,
                                                     int* __restrict__ table,
                                                     int* __restrict__ slot_token,
                                                     int* __restrict__ tok2slot) {
  __shared__ int cnt[NE], offs[NE], cur[NE];
  const int tid = threadIdx.x, lane = tid & 63;
  for (int i = tid; i < MP; i += 1024) slot_token[i] = -1;
  if (tid < NE) cnt[tid] = 0;
  __syncthreads();
  int myE[8];
#pragma unroll
  for (int c = 0; c < 8; ++c) myE[c] = idx[c * 1024 + tid];
#pragma unroll
  for (int c = 0; c < 8; ++c) {
    int e = myE[c];
#pragma unroll
    for (int ex = 0; ex < NE; ++ex) {
      unsigned long long m = __ballot(e == ex);
      if (lane == 0 && m) atomicAdd(&cnt[ex], __popcll(m));
    }
  }
  __syncthreads();
  if (tid == 0) {
    int cum = 0;
    for (int e = 0; e < NE; ++e) {
      offs[e] = cum; cur[e] = 0;
      int nb = (cnt[e] + 127) >> 7;
      int bb = cum >> 7;
      for (int b = 0; b < nb; ++b) table[bb + b] = e;
      cum += nb << 7;
    }
    for (int b = cum >> 7; b < NBR; ++b) table[b] = -1;
  }
  __syncthreads();
#pragma unroll
  for (int c = 0; c < 8; ++c) {
    int e = myE[c];
    int pos = 0;
#pragma unroll
    for (int ex = 0; ex < NE; ++ex) {
      unsigned long long m = __ballot(e == ex);
      if (e == ex) {
        int rank = __popcll(m & ((1ull << lane) - 1ull));
        int leader = __ffsll(m) - 1;
        int base = 0;
        if (lane == leader) base = atomicAdd(&cur[ex], __popcll(m));
        base = __shfl(base, leader);
        pos = offs[ex] + base + rank;
      }
    }
    slot_token[pos] = (c * 1024 + tid) >> 1;
    tok2slot[c * 1024 + tid] = pos;
  }
}

__global__ void gather_kernel(const float* __restrict__ X, const int* __restrict__ slot_token,
                              uint4* __restrict__ Xg) {
  int gid = blockIdx.x * 256 + threadIdx.x;   // MP*128 threads, 8 elems each
  int row = gid >> 7, j = (gid & 127) << 3;
  int t = slot_token[row];
  uint4 o;
  if (t >= 0) {
    const float4* p = (const float4*)(X + (size_t)t * DIM + j);
    float4 a = p[0], b = p[1];
    o.x = pack2(a.x, a.y); o.y = pack2(a.z, a.w);
    o.z = pack2(b.x, b.y); o.w = pack2(b.z, b.w);
  } else {
    o = uint4{0u, 0u, 0u, 0u};
  }
  Xg[gid] = o;
}

// both weight tensors in one launch
__global__ void convert_kernel(const float4* __restrict__ srcGu, uint2* __restrict__ dstGu,
                               const float4* __restrict__ srcD, uint2* __restrict__ dstD) {
  const int n1 = NE * 2 * HID * DIM / 4;
  int i = blockIdx.x * 256 + threadIdx.x;
  float4 v; uint2* dp;
  if (i < n1) { v = srcGu[i]; dp = dstGu + i; }
  else        { v = srcD[i - n1]; dp = dstD + (i - n1); }
  uint2 o; o.x = pack2(v.x, v.y); o.y = pack2(v.z, v.w);
  *dp = o;
}

__global__ void combine_kernel(const float* __restrict__ Obuf, const int* __restrict__ tok2slot,
                               const float* __restrict__ wts, float4* __restrict__ out) {
  int t = blockIdx.x, c = threadIdx.x;            // 4096 blocks x 256 threads
  int s0 = tok2slot[2 * t], s1 = tok2slot[2 * t + 1];
  float w0 = wts[2 * t], w1 = wts[2 * t + 1];
  float4 a = ((const float4*)(Obuf + (size_t)s0 * OUTD))[c];
  float4 b = ((const float4*)(Obuf + (size_t)s1 * OUTD))[c];
  out[(size_t)t * (OUTD / 4) + c] =
      float4{w0 * a.x + w1 * b.x, w0 * a.y + w1 * b.y, w0 * a.z + w1 * b.z, w0 * a.w + w1 * b.w};
}

// ---------- GEMM1: h = silu(Xg*Wg^T) * (Xg*Wu^T), BK=64 ----------
// grid (32, 72): x = H col-block (64 gate + 64 up), y = row-block
__global__ __launch_bounds__(256) void gemm1_kernel(
    const unsigned short* __restrict__ Xg,   // [MP, DIM]
    const unsigned short* __restrict__ Wgu,  // [NE, 2*HID, DIM]
    unsigned short* __restrict__ Hbuf,       // [MP, HID]
    const int* __restrict__ table) {
  int e = table[blockIdx.y];
  if (e < 0) return;
  const int tid = threadIdx.x;
  const int lane = tid & 63, wave = tid >> 6;
  const int wm = wave >> 1, wn = wave & 1;
  const int lr = lane & 15, quad = lane >> 4;

  __shared__ bf16 As[128 * 64];
  __shared__ bf16 Bg[64 * 64];
  __shared__ bf16 Bu[64 * 64];

  const unsigned short* A_base  = Xg  + (size_t)blockIdx.y * 128 * DIM;
  const unsigned short* Wg_base = Wgu + (size_t)e * 2 * HID * DIM + (size_t)(blockIdx.x * 64) * DIM;
  const unsigned short* Wu_base = Wg_base + (size_t)HID * DIM;

  f32x4 accg[4][2] = {}; f32x4 accu[4][2] = {};

  for (int kt = 0; kt < DIM / 64; ++kt) {   // 16 iters
    const int kb = kt * 64;
#pragma unroll
    for (int i = 0; i < 4; ++i) {           // A: 128 rows x 8 chunks
      int s = i * 256 + tid, row = s >> 3, pc = s & 7, gc = pc ^ (row & 7);
      cp16(A_base + (size_t)row * DIM + kb + gc * 8, (void*)(As + row * 64 + pc * 8));
    }
#pragma unroll
    for (int i = 0; i < 2; ++i) {           // Bg/Bu: 64 rows x 8 chunks each
      int s = i * 256 + tid, row = s >> 3, pc = s & 7, gc = pc ^ (row & 7);
      cp16(Wg_base + (size_t)row * DIM + kb + gc * 8, (void*)(Bg + row * 64 + pc * 8));
      cp16(Wu_base + (size_t)row * DIM + kb + gc * 8, (void*)(Bu + row * 64 + pc * 8));
    }
    __syncthreads();
#pragma unroll
    for (int ks = 0; ks < 2; ++ks) {
      bf16x8 a[4], bg[2], bu[2];
#pragma unroll
      for (int i = 0; i < 4; ++i) {
        int row = wm * 64 + i * 16 + lr;
        int pc = (ks * 4 + quad) ^ (row & 7);
        a[i] = *(const bf16x8*)(As + row * 64 + pc * 8);
      }
#pragma unroll
      for (int j = 0; j < 2; ++j) {
        int row = wn * 32 + j * 16 + lr;
        int pc = (ks * 4 + quad) ^ (row & 7);
        bg[j] = *(const bf16x8*)(Bg + row * 64 + pc * 8);
        bu[j] = *(const bf16x8*)(Bu + row * 64 + pc * 8);
      }
#pragma unroll
      for (int i = 0; i < 4; ++i)
#pragma unroll
        for (int j = 0; j < 2; ++j) {
          accg[i][j] = __builtin_amdgcn_mfma_f32_16x16x32_bf16(a[i], bg[j], accg[i][j], 0, 0, 0);
          accu[i][j] = __builtin_amdgcn_mfma_f32_16x16x32_bf16(a[i], bu[j], accu[i][j], 0, 0, 0);
        }
    }
    __syncthreads();
  }

  const int rowBase = blockIdx.y * 128 + wm * 64;
  const int colBase = blockIdx.x * 64 + wn * 32;
#pragma unroll
  for (int i = 0; i < 4; ++i)
#pragma unroll
    for (int r = 0; r < 4; ++r) {
      int row = rowBase + i * 16 + quad * 4 + r;
#pragma unroll
      for (int j = 0; j < 2; ++j) {
        float g = accg[i][j][r], u = accu[i][j][r];
        float s = g / (1.0f + __expf(-g));
        Hbuf[(size_t)row * HID + colBase + j * 16 + lr] = f2bf(s * u);
      }
    }
}

// ---------- GEMM2: Obuf[slot] = H * Wd^T, BK=64 ----------
// grid (8, 72): x = OUT col-block (128), y = row-block
__global__ __launch_bounds__(256) void gemm2_kernel(
    const unsigned short* __restrict__ Hbuf, // [MP, HID]
    const unsigned short* __restrict__ Wd,   // [NE, OUTD, HID]
    float* __restrict__ Obuf,                // [MP, OUTD]
    const int* __restrict__ table) {
  int e = table[blockIdx.y];
  if (e < 0) return;
  const int tid = threadIdx.x;
  const int lane = tid & 63, wave = tid >> 6;
  const int wm = wave >> 1, wn = wave & 1;
  const int lr = lane & 15, quad = lane >> 4;

  __shared__ bf16 As[128 * 64];
  __shared__ bf16 Bs[128 * 64];

  const unsigned short* A_base = Hbuf + (size_t)blockIdx.y * 128 * HID;
  const unsigned short* B_base = Wd + (size_t)e * OUTD * HID + (size_t)(blockIdx.x * 128) * HID;

  f32x4 acc[4][4] = {};

  for (int kt = 0; kt < HID / 64; ++kt) {   // 32 iters
    const int kb = kt * 64;
#pragma unroll
    for (int i = 0; i < 4; ++i) {
      int s = i * 256 + tid, row = s >> 3, pc = s & 7, gc = pc ^ (row & 7);
      cp16(A_base + (size_t)row * HID + kb + gc * 8, (void*)(As + row * 64 + pc * 8));
      cp16(B_base + (size_t)row * HID + kb + gc * 8, (void*)(Bs + row * 64 + pc * 8));
    }
    __syncthreads();
#pragma unroll
    for (int ks = 0; ks < 2; ++ks) {
      bf16x8 a[4], b[4];
#pragma unroll
      for (int i = 0; i < 4; ++i) {
        int row = wm * 64 + i * 16 + lr;
        int pc = (ks * 4 + quad) ^ (row & 7);
        a[i] = *(const bf16x8*)(As + row * 64 + pc * 8);
      }
#pragma unroll
      for (int j = 0; j < 4; ++j) {
        int row = wn * 64 + j * 16 + lr;
        int pc = (ks * 4 + quad) ^ (row & 7);
        b[j] = *(const bf16x8*)(Bs + row * 64 + pc * 8);
      }
#pragma unroll
      for (int i = 0; i < 4; ++i)
#pragma unroll
        for (int j = 0; j < 4; ++j)
          acc[i][j] = __builtin_amdgcn_mfma_f32_16x16x32_bf16(a[i], b[j], acc[i][j], 0, 0, 0);
    }
    __syncthreads();
  }

  const int rowBase = blockIdx.y * 128 + wm * 64;
  const int colBase = blockIdx.x * 128 + wn * 64;
#pragma unroll
  for (int i = 0; i < 4; ++i)
#pragma unroll
    for (int r = 0; r < 4; ++r) {
      int row = rowBase + i * 16 + quad * 4 + r;
      float* Orow = Obuf + (size_t)row * OUTD + colBase;
#pragma unroll
      for (int j = 0; j < 4; ++j)
        Orow[j * 16 + lr] = acc[i][j][r];
    }
}

extern "C" void kernel_launch(void* const* d_in, const int* in_sizes, int n_in,
                              void* d_out, int out_size, void* d_ws, size_t ws_size,
                              hipStream_t stream) {
  const float* X     = (const float*)d_in[0];
  const int*   idx   = (const int*)d_in[1];
  const float* wts   = (const float*)d_in[2];
  const float* WguF  = (const float*)d_in[3];
  const float* WdF   = (const float*)d_in[4];
  float* out = (float*)d_out;

  char* base = (char*)d_ws;
  unsigned short* Wgu = (unsigned short*)(base + WGU_OFF);
  unsigned short* Wd  = (unsigned short*)(base + WD_OFF);
  unsigned short* Xg  = (unsigned short*)(base + XG_OFF);
  unsigned short* Hb  = (unsigned short*)(base + H_OFF);
  float* Obuf         = (float*)(base + WGU_OFF);   // aliases Wgu (dead after gemm1)
  int*   slot_token = (int*)(base + TK_OFF);
  int*   table      = (int*)(base + META_OFF);
  int*   tok2slot   = (int*)(base + T2S_OFF);

  route_kernel<<<1, 1024, 0, stream>>>(idx, table, slot_token, tok2slot);
  gather_kernel<<<(MP * 128) / 256, 256, 0, stream>>>(X, slot_token, (uint4*)Xg);
  {
    const int nTot = (NE * 2 * HID * DIM + NE * OUTD * HID) / 4;
    convert_kernel<<<nTot / 256, 256, 0, stream>>>((const float4*)WguF, (uint2*)Wgu,
                                                   (const float4*)WdF, (uint2*)Wd);
  }
  gemm1_kernel<<<dim3(HID / 64, NBR), 256, 0, stream>>>(Xg, Wgu, Hb, table);
  gemm2_kernel<<<dim3(OUTD / 128, NBR), 256, 0, stream>>>(Hb, Wd, Obuf, table);
  combine_kernel<<<TOKS, 256, 0, stream>>>(Obuf, tok2slot, wts, (float4*)out);
}